// Round 1
// baseline (172.485 us; speedup 1.0000x reference)
//
#include <hip/hip_runtime.h>
#include <math.h>

// Problem constants: B=32, HW=4096 (64x64), C=256, G=32, CG=8, n=1024 samples.
// One workgroup per sample (b,g). gx tile (8x64x64 fp32 = 128KB) lives in LDS.

#define NBLK 1024
#define NTHR 512

__global__ __launch_bounds__(512) void fused_ema_kernel(
    const float* __restrict__ x,     // (32, 4096, 256)
    const float* __restrict__ w1,    // (8,8)
    const float* __restrict__ b1,    // (8)
    const float* __restrict__ w3,    // (8,8,3,3)
    const float* __restrict__ b3,    // (8)
    const float* __restrict__ gn_w,  // (8)
    const float* __restrict__ gn_b,  // (8)
    float* __restrict__ out)         // (32, 4096, 256)
{
    __shared__ float gx[8 * 4096];   // [i][y][x], 128 KB
    __shared__ float Rs[8][64];      // row sums  (sum over x)
    __shared__ float Cs[8][64];      // col sums  (sum over y)
    __shared__ float sg[8][128];     // sigmoid gates: [:, :64]=sh(y), [:,64:]=sw(x)
    __shared__ float t1s[8][64];     // x21[i]*a[i]*sh[i][y]
    __shared__ float weff[8][9];     // sum_o x11[o]*w3[o,i,ky,kx]
    __shared__ float Ai[8], Ci[8], Ti[8];
    __shared__ float m2s[8], x11s[8], x21s[8];
    __shared__ float wconst_s;

    const int t = threadIdx.x;
    const int n = blockIdx.x;
    const int b = n >> 5;
    const int g = n & 31;

    // ---------------- Phase 1: load x -> LDS (gx[i][y][x]) -----------------
    // float idx of (p, i): (b*4096+p)*256 + g*8 + i  -> float4 idx: (b*4096+p)*64 + g*2 + half
    {
        const float4* x4 = reinterpret_cast<const float4*>(x) + (size_t)b * 4096 * 64 + g * 2;
#pragma unroll
        for (int k = 0; k < 16; ++k) {
            int f = k * 512 + t;           // 0..8191 float4s
            int p = f >> 1;
            int half = f & 1;
            float4 v = x4[(size_t)p * 64 + half];
            float* dst = &gx[(half * 4) * 4096 + p];
            dst[0 * 4096] = v.x;
            dst[1 * 4096] = v.y;
            dst[2 * 4096] = v.z;
            dst[3 * 4096] = v.w;
        }
    }
    __syncthreads();

    // ---------------- Phase 2: row sums, col sums, totals -------------------
    {
        // col sums: thread (i = t>>6 == wave id, xcol = lane)
        int i = t >> 6, xcol = t & 63;
        float acc = 0.f;
        for (int y = 0; y < 64; ++y) acc += gx[i * 4096 + y * 64 + xcol];
        Cs[i][xcol] = acc;
        float s = acc;
#pragma unroll
        for (int off = 32; off; off >>= 1) s += __shfl_xor(s, off);
        if (xcol == 0) Ti[i] = s;

        // row sums (diagonal x offset to avoid same-bank column reads)
        int y = t & 63;
        float racc = 0.f;
        for (int k = 0; k < 64; ++k) {
            int xc = (k + t) & 63;
            racc += gx[i * 4096 + y * 64 + xc];
        }
        Rs[i][y] = racc;
    }
    __syncthreads();

    // ---------------- Phase 3: gate matmul (8x8) + sigmoid ------------------
    {
#pragma unroll
        for (int k = 0; k < 2; ++k) {
            int idx = k * 512 + t;     // 0..1023
            int o = idx >> 7, p = idx & 127;   // p<64: y-gate, p>=64: x-gate
            float val = b1[o];
#pragma unroll
            for (int i = 0; i < 8; ++i) {
                float cv = (p < 64) ? Rs[i][p] : Cs[i][p - 64];
                val += w1[o * 8 + i] * (cv * (1.0f / 64.0f));
            }
            sg[o][p] = 1.0f / (1.0f + expf(-val));
        }
    }
    __syncthreads();

    // ---------------- Phase 4: instance-norm stats of gated -----------------
    {
        int i = t >> 6, xcol = t & 63;
        float swv = sg[i][64 + xcol];
        float s = 0.f, s2 = 0.f;
        for (int y = 0; y < 64; ++y) {
            float gv = gx[i * 4096 + y * 64 + xcol] * sg[i][y] * swv;
            s += gv;
            s2 += gv * gv;
        }
#pragma unroll
        for (int off = 32; off; off >>= 1) {
            s += __shfl_xor(s, off);
            s2 += __shfl_xor(s2, off);
        }
        if (xcol == 0) {
            float mu = s * (1.0f / 4096.0f);
            float var = s2 * (1.0f / 4096.0f) - mu * mu;
            float a = rsqrtf(var + 1e-5f) * gn_w[i];
            Ai[i] = a;
            Ci[i] = gn_b[i] - mu * a;
        }
    }
    __syncthreads();

    // ------- Phase 5a: conv channel means via rectangle sums (wave 0) -------
    if (t < 64) {
        int o = t >> 3, i = t & 7;
        float T = Ti[i];
        float part = 0.f;
#pragma unroll
        for (int ky = 0; ky < 3; ++ky) {
            int dy = ky - 1;
#pragma unroll
            for (int kx = 0; kx < 3; ++kx) {
                int dx = kx - 1;
                float S = T;
                int er = (dy < 0) ? 63 : 0;
                int ec = (dx < 0) ? 63 : 0;
                if (dy != 0) S -= Rs[i][er];
                if (dx != 0) S -= Cs[i][ec];
                if (dy != 0 && dx != 0) S += gx[i * 4096 + er * 64 + ec];
                part += w3[((o * 8 + i) * 3 + ky) * 3 + kx] * S;
            }
        }
#pragma unroll
        for (int off = 4; off; off >>= 1) part += __shfl_xor(part, off);
        if (i == 0) m2s[o] = part * (1.0f / 4096.0f) + b3[o];
    }
    __syncthreads();

    // ------- Phase 5b: the two 8-way softmaxes ------------------------------
    if (t < 8) {
        // x21 = softmax(conv means)
        float mx = m2s[0];
#pragma unroll
        for (int o = 1; o < 8; ++o) mx = fmaxf(mx, m2s[o]);
        float sum = 0.f;
#pragma unroll
        for (int o = 0; o < 8; ++o) sum += expf(m2s[o] - mx);
        x21s[t] = expf(m2s[t] - mx) / sum;
        // x11 = softmax(x1 means) ; x1 mean over pixels == gn_b exactly
        float mx1 = gn_b[0];
#pragma unroll
        for (int o = 1; o < 8; ++o) mx1 = fmaxf(mx1, gn_b[o]);
        float sum1 = 0.f;
#pragma unroll
        for (int o = 0; o < 8; ++o) sum1 += expf(gn_b[o] - mx1);
        x11s[t] = expf(gn_b[t] - mx1) / sum1;
    }
    __syncthreads();

    // ------- Phase 5c: collapsed conv filter, t1, constants -----------------
    if (t < 72) {
        int i = t / 9, k = t % 9;
        float acc = 0.f;
#pragma unroll
        for (int o = 0; o < 8; ++o) acc += x11s[o] * w3[(o * 8 + i) * 9 + k];
        weff[i][k] = acc;
    }
    {
        int i = t >> 6, y = t & 63;
        t1s[i][y] = x21s[i] * Ai[i] * sg[i][y];
    }
    if (t == 0) {
        float wc = 0.f;
#pragma unroll
        for (int o = 0; o < 8; ++o) wc += x11s[o] * b3[o];
#pragma unroll
        for (int i = 0; i < 8; ++i) wc += x21s[i] * Ci[i];
        wconst_s = wc;
    }
    __syncthreads();

    // ---------------- Phase 6: per-pixel weights + output -------------------
    {
        const int xcol = t & 63;
        const int ybase = t >> 6;          // wave id -> y uniform per wave
        const bool xl = (xcol == 0), xr = (xcol == 63);
        float4* out4 = reinterpret_cast<float4*>(out) + (size_t)b * 4096 * 64 + g * 2;

        for (int r = 0; r < 8; ++r) {
            const int y = ybase + r * 8;   // uniform within wave
            float wsum = wconst_s;
            float gxv[8];
#pragma unroll
            for (int i = 0; i < 8; ++i) {
                const int base = i * 4096 + y * 64 + xcol;
                float conv = 0.f;
#pragma unroll
                for (int dy = -1; dy <= 1; ++dy) {
                    const int yy = y + dy;
                    if (yy < 0 || yy > 63) continue;   // wave-uniform branch
                    const float* rp = &gx[i * 4096 + yy * 64 + xcol];
                    const float* wp = &weff[i][(dy + 1) * 3];
                    float vm = rp[xl ? 0 : -1];
                    if (xl) vm = 0.f;
                    float v0 = rp[0];
                    float vp = rp[xr ? 0 : 1];
                    if (xr) vp = 0.f;
                    conv += wp[0] * vm + wp[1] * v0 + wp[2] * vp;
                }
                float g0 = gx[base];
                gxv[i] = g0;
                wsum += conv + t1s[i][y] * sg[i][64 + xcol] * g0;
            }
            float sig = 1.0f / (1.0f + expf(-wsum));
            float4 o0, o1;
            o0.x = gxv[0] * sig; o0.y = gxv[1] * sig;
            o0.z = gxv[2] * sig; o0.w = gxv[3] * sig;
            o1.x = gxv[4] * sig; o1.y = gxv[5] * sig;
            o1.z = gxv[6] * sig; o1.w = gxv[7] * sig;
            const size_t p = (size_t)(y * 64 + xcol);
            out4[p * 64 + 0] = o0;
            out4[p * 64 + 1] = o1;
        }
    }
}

extern "C" void kernel_launch(void* const* d_in, const int* in_sizes, int n_in,
                              void* d_out, int out_size, void* d_ws, size_t ws_size,
                              hipStream_t stream) {
    const float* x    = (const float*)d_in[0];
    const float* w1   = (const float*)d_in[1];
    const float* b1   = (const float*)d_in[2];
    const float* w3   = (const float*)d_in[3];
    const float* b3   = (const float*)d_in[4];
    const float* gn_w = (const float*)d_in[5];
    const float* gn_b = (const float*)d_in[6];
    float* out = (float*)d_out;

    hipLaunchKernelGGL(fused_ema_kernel, dim3(NBLK), dim3(NTHR), 0, stream,
                       x, w1, b1, w3, b3, gn_w, gn_b, out);
}

// Round 2
// 107.815 us; speedup vs baseline: 1.5998x; 1.5998x over previous
//
#include <hip/hip_runtime.h>
#include <math.h>

// B=32, HW=4096 (64x64), C=256, G=32, CG=8, n=1024 samples of (8,64,64).
// One workgroup per sample. gx tile (128 KB fp32) in LDS.
// 1024 threads (16 waves). XCD-swizzled blockIdx so the 4 samples sharing
// each 128B cache line (same b, g-quad) run on the same XCD back-to-back.

#define NBLK 1024
#define NTHR 1024

__global__ __launch_bounds__(1024) void fused_ema_kernel(
    const float* __restrict__ x,     // (32, 4096, 256)
    const float* __restrict__ w1,    // (8,8)
    const float* __restrict__ b1,    // (8)
    const float* __restrict__ w3,    // (8,8,3,3)
    const float* __restrict__ b3,    // (8)
    const float* __restrict__ gn_w,  // (8)
    const float* __restrict__ gn_b,  // (8)
    float* __restrict__ out)         // (32, 4096, 256)
{
    __shared__ float gx[8 * 4096];     // [i][y][x], 128 KB
    __shared__ float Rs[8][64];        // row sums (over x)
    __shared__ float Cs[8][64];        // col sums (over y)
    __shared__ float RsPart[2][8][64];
    __shared__ float CsPart[2][8][64];
    __shared__ float sg[8][128];       // gates: [:, :64]=sh(y), [:,64:]=sw(x)
    __shared__ float t1s[8][64];       // x21[i]*a[i]*sh[i][y]
    __shared__ float weff[8][9];       // sum_o x11[o]*w3[o,i,:,:]
    __shared__ float Ai[8], Ci[8], Ti[8];
    __shared__ float m2s[8], x11s[8], x21s[8];
    __shared__ float sPart[16], s2Part[16];
    __shared__ float wconst_s;

    const int t = threadIdx.x;
    // XCD-aware swizzle: bid%8 = XCD (round-robin dispatch). Give each XCD
    // 32 consecutive quads; quad members at adjacent slots on that XCD.
    const int bi = blockIdx.x;
    const int n = ((bi & 7) * 32 + ((bi >> 3) >> 2)) * 4 + ((bi >> 3) & 3);
    const int b = n >> 5;
    const int g = n & 31;

    // ---------------- Phase 1: load x -> LDS (gx[i][y][x]) -----------------
    {
        const float4* x4 = reinterpret_cast<const float4*>(x) + (size_t)b * 4096 * 64 + g * 2;
#pragma unroll
        for (int k = 0; k < 8; ++k) {
            int f = k * 1024 + t;          // 0..8191 float4s
            int p = f >> 1;
            int half = f & 1;
            float4 v = x4[(size_t)p * 64 + half];
            float* dst = &gx[(half * 4) * 4096 + p];
            dst[0 * 4096] = v.x;
            dst[1 * 4096] = v.y;
            dst[2 * 4096] = v.z;
            dst[3 * 4096] = v.w;
        }
    }
    __syncthreads();

    // ---------------- Phase 2: row/col partial sums -------------------------
    {
        const int i = t >> 7, l = t & 127;
        const int xcol = l & 63, yh = l >> 6;
        float acc = 0.f;
        for (int y = yh * 32; y < yh * 32 + 32; ++y)
            acc += gx[i * 4096 + y * 64 + xcol];
        CsPart[yh][i][xcol] = acc;

        const int y = l & 63, xh = l >> 6;
        float racc = 0.f;
        for (int k = 0; k < 32; ++k) {
            int xc = xh * 32 + ((k + t) & 31);   // diagonal: bank-conflict-free
            racc += gx[i * 4096 + y * 64 + xc];
        }
        RsPart[xh][i][y] = racc;
    }
    __syncthreads();
    if (t < 512) {
        const int i = t >> 6, j = t & 63;
        float c = CsPart[0][i][j] + CsPart[1][i][j];
        Cs[i][j] = c;
        Rs[i][j] = RsPart[0][i][j] + RsPart[1][i][j];
        float s = c;
#pragma unroll
        for (int off = 32; off; off >>= 1) s += __shfl_xor(s, off);
        if (j == 0) Ti[i] = s;
    }
    __syncthreads();

    // ---------------- Phase 3: gate matmul (8x8) + sigmoid ------------------
    {
        const int o = t >> 7, p = t & 127;   // p<64: y-gate, p>=64: x-gate
        float val = b1[o];
#pragma unroll
        for (int i = 0; i < 8; ++i) {
            float cv = (p < 64) ? Rs[i][p] : Cs[i][p - 64];
            val += w1[o * 8 + i] * (cv * (1.0f / 64.0f));
        }
        sg[o][p] = 1.0f / (1.0f + expf(-val));
    }
    __syncthreads();

    // ---------------- Phase 4: instance-norm stats of gated -----------------
    {
        const int i = t >> 7, l = t & 127;
        const int xcol = l & 63, yh = l >> 6;
        const float swv = sg[i][64 + xcol];
        float s = 0.f, s2 = 0.f;
        for (int y = yh * 32; y < yh * 32 + 32; ++y) {
            float gv = gx[i * 4096 + y * 64 + xcol] * sg[i][y] * swv;
            s += gv;
            s2 += gv * gv;
        }
#pragma unroll
        for (int off = 32; off; off >>= 1) {
            s += __shfl_xor(s, off);
            s2 += __shfl_xor(s2, off);
        }
        if ((t & 63) == 0) {
            sPart[t >> 6] = s;
            s2Part[t >> 6] = s2;
        }
    }
    __syncthreads();

    // ---- Phase 5a: finalize norm stats (t<8) + conv means (t<64) -----------
    if (t < 8) {
        float s  = sPart[2 * t] + sPart[2 * t + 1];
        float s2 = s2Part[2 * t] + s2Part[2 * t + 1];
        float mu = s * (1.0f / 4096.0f);
        float var = s2 * (1.0f / 4096.0f) - mu * mu;
        float a = rsqrtf(var + 1e-5f) * gn_w[t];
        Ai[t] = a;
        Ci[t] = gn_b[t] - mu * a;
    }
    if (t < 64) {
        const int o = t >> 3, i = t & 7;
        const float T = Ti[i];
        float part = 0.f;
#pragma unroll
        for (int ky = 0; ky < 3; ++ky) {
            int dy = ky - 1;
#pragma unroll
            for (int kx = 0; kx < 3; ++kx) {
                int dx = kx - 1;
                float S = T;
                int er = (dy < 0) ? 63 : 0;
                int ec = (dx < 0) ? 63 : 0;
                if (dy != 0) S -= Rs[i][er];
                if (dx != 0) S -= Cs[i][ec];
                if (dy != 0 && dx != 0) S += gx[i * 4096 + er * 64 + ec];
                part += w3[((o * 8 + i) * 3 + ky) * 3 + kx] * S;
            }
        }
#pragma unroll
        for (int off = 4; off; off >>= 1) part += __shfl_xor(part, off);
        if (i == 0) m2s[o] = part * (1.0f / 4096.0f) + b3[o];
    }
    __syncthreads();

    // ---- Phase 5b: the two 8-way softmaxes ---------------------------------
    if (t < 8) {
        float mx = m2s[0];
#pragma unroll
        for (int o = 1; o < 8; ++o) mx = fmaxf(mx, m2s[o]);
        float sum = 0.f;
#pragma unroll
        for (int o = 0; o < 8; ++o) sum += expf(m2s[o] - mx);
        x21s[t] = expf(m2s[t] - mx) / sum;
        // x1 per-channel spatial mean == gn_b exactly (normalized field)
        float mx1 = gn_b[0];
#pragma unroll
        for (int o = 1; o < 8; ++o) mx1 = fmaxf(mx1, gn_b[o]);
        float sum1 = 0.f;
#pragma unroll
        for (int o = 0; o < 8; ++o) sum1 += expf(gn_b[o] - mx1);
        x11s[t] = expf(gn_b[t] - mx1) / sum1;
    }
    __syncthreads();

    // ---- Phase 5c: collapsed conv filter, t1, constants --------------------
    if (t < 72) {
        const int i = t / 9, k = t % 9;
        float acc = 0.f;
#pragma unroll
        for (int o = 0; o < 8; ++o) acc += x11s[o] * w3[(o * 8 + i) * 9 + k];
        weff[i][k] = acc;
    }
    if (t < 512) {
        const int i = t >> 6, y = t & 63;
        t1s[i][y] = x21s[i] * Ai[i] * sg[i][y];
    }
    if (t == 0) {
        float wc = 0.f;
#pragma unroll
        for (int o = 0; o < 8; ++o) wc += x11s[o] * b3[o];
#pragma unroll
        for (int i = 0; i < 8; ++i) wc += x21s[i] * Ci[i];
        wconst_s = wc;
    }
    __syncthreads();

    // ---------------- Phase 6: per-pixel weights + output -------------------
    {
        const int xcol = t & 63;
        const int ybase = t >> 6;          // 0..15, wave-uniform
        const bool xl = (xcol == 0), xr = (xcol == 63);
        float4* out4 = reinterpret_cast<float4*>(out) + (size_t)b * 4096 * 64 + g * 2;

        for (int r = 0; r < 4; ++r) {
            const int y = ybase + r * 16;  // uniform within wave
            float wsum = wconst_s;
            float gxv[8];
#pragma unroll
            for (int i = 0; i < 8; ++i) {
                const int base = i * 4096 + y * 64 + xcol;
                float conv = 0.f;
#pragma unroll
                for (int dy = -1; dy <= 1; ++dy) {
                    const int yy = y + dy;
                    if (yy < 0 || yy > 63) continue;   // wave-uniform branch
                    const float* rp = &gx[i * 4096 + yy * 64 + xcol];
                    const float* wp = &weff[i][(dy + 1) * 3];
                    float vm = rp[xl ? 0 : -1];
                    if (xl) vm = 0.f;
                    float v0 = rp[0];
                    float vp = rp[xr ? 0 : 1];
                    if (xr) vp = 0.f;
                    conv += wp[0] * vm + wp[1] * v0 + wp[2] * vp;
                }
                float g0 = gx[base];
                gxv[i] = g0;
                wsum += conv + t1s[i][y] * sg[i][64 + xcol] * g0;
            }
            float sig = 1.0f / (1.0f + expf(-wsum));
            float4 o0, o1;
            o0.x = gxv[0] * sig; o0.y = gxv[1] * sig;
            o0.z = gxv[2] * sig; o0.w = gxv[3] * sig;
            o1.x = gxv[4] * sig; o1.y = gxv[5] * sig;
            o1.z = gxv[6] * sig; o1.w = gxv[7] * sig;
            const size_t p = (size_t)(y * 64 + xcol);
            out4[p * 64 + 0] = o0;
            out4[p * 64 + 1] = o1;
        }
    }
}

extern "C" void kernel_launch(void* const* d_in, const int* in_sizes, int n_in,
                              void* d_out, int out_size, void* d_ws, size_t ws_size,
                              hipStream_t stream) {
    const float* x    = (const float*)d_in[0];
    const float* w1   = (const float*)d_in[1];
    const float* b1   = (const float*)d_in[2];
    const float* w3   = (const float*)d_in[3];
    const float* b3   = (const float*)d_in[4];
    const float* gn_w = (const float*)d_in[5];
    const float* gn_b = (const float*)d_in[6];
    float* out = (float*)d_out;

    hipLaunchKernelGGL(fused_ema_kernel, dim3(NBLK), dim3(NTHR), 0, stream,
                       x, w1, b1, w3, b3, gn_w, gn_b, out);
}

// Round 3
// 89.533 us; speedup vs baseline: 1.9265x; 1.2042x over previous
//
#include <hip/hip_runtime.h>
#include <math.h>

// B=32, HW=4096 (64x64), C=256, G=32, CG=8 -> 1024 samples of (8,64,64).
// One workgroup per sample; gx resident in LDS as packed bf16 pairs
// (2 px per u32, channel stride padded) -> 80.5 KB LDS -> 2 blocks/CU.

#define NBLK 1024
#define NTHR 512
#define CSTR 2052   // u32 per channel (2*2052 = 4104 bf16 = 4096 px + 8 pad)
#define USTR 4104   // ushort per channel

typedef unsigned int uint;
typedef unsigned short ushort;

__device__ __forceinline__ uint pk2(float a, float b) {   // 2x f32 -> packed bf16 (RNE)
    uint ua = __builtin_bit_cast(uint, a);
    uint ub = __builtin_bit_cast(uint, b);
    ua = (ua + 0x7FFFu + ((ua >> 16) & 1u)) >> 16;
    ub = (ub + 0x7FFFu + ((ub >> 16) & 1u)) >> 16;
    return ua | (ub << 16);
}
__device__ __forceinline__ float blo(uint u) { return __builtin_bit_cast(float, u << 16); }
__device__ __forceinline__ float bhi(uint u) { return __builtin_bit_cast(float, u & 0xFFFF0000u); }
__device__ __forceinline__ float bfs(ushort s) { return __builtin_bit_cast(float, ((uint)s) << 16); }
__device__ __forceinline__ float sigm(float v) { return 1.0f / (1.0f + __expf(-v)); }
__device__ __forceinline__ uint pksig(float a, float b) { // 2x sigmoid -> u16 fixed-point
    return (uint)(a * 65535.0f + 0.5f) | ((uint)(b * 65535.0f + 0.5f) << 16);
}

__global__ __launch_bounds__(512, 4) void fused_ema_kernel(
    const float* __restrict__ x,     // (32, 4096, 256)
    const float* __restrict__ w1,    // (8,8)
    const float* __restrict__ b1,    // (8)
    const float* __restrict__ w3,    // (8,8,3,3)
    const float* __restrict__ b3,    // (8)
    const float* __restrict__ gn_w,  // (8)
    const float* __restrict__ gn_b,  // (8)
    float* __restrict__ out)         // (32, 4096, 256)
{
    __shared__ __align__(16) uint  gxp[8 * CSTR];   // 65,664 B: bf16-pair gx
    __shared__ __align__(16) float sg[8 * 128];     // 4 KB gates: [:64]=sh(y) [64:]=sw(x)
    __shared__ __align__(16) float uni[2048];       // 8 KB: Rs|Cs, later u16 sigmoid field
    __shared__ __align__(16) float t1s[8 * 64];     // 2 KB: x21*Ai*sh[y]
    __shared__ float weff[72];                      // sum_o x11[o]*w3[o,i,:,:]
    __shared__ float Ti[8], m2s[8], Ai[8], Ci[8], x11s[8], x21s[8];
    __shared__ float wconst_s;

    const int t = threadIdx.x;
    // quad (same b, 4 consecutive g sharing each 128B line) -> same XCD, close slots
    const int bi = blockIdx.x;
    const int n = ((bi & 7) * 32 + ((bi >> 3) >> 2)) * 4 + ((bi >> 3) & 3);
    const int b = n >> 5;
    const int g = n & 31;

    // ---------------- Phase 1: load x -> LDS (bf16 pairs) -------------------
    {
        const float4* x4 = reinterpret_cast<const float4*>(x) + (size_t)b * 4096 * 64 + g * 2;
#pragma unroll
        for (int k = 0; k < 8; ++k) {
            int idx = k * 512 + t;        // 0..4095
            int q = idx >> 1;             // pixel pair 0..2047
            int half = idx & 1;
            float4 v0 = x4[(size_t)q * 128 + half];        // px 2q
            float4 v1 = x4[(size_t)q * 128 + 64 + half];   // px 2q+1
            int ch = half * 4;
            gxp[(ch + 0) * CSTR + q] = pk2(v0.x, v1.x);
            gxp[(ch + 1) * CSTR + q] = pk2(v0.y, v1.y);
            gxp[(ch + 2) * CSTR + q] = pk2(v0.z, v1.z);
            gxp[(ch + 3) * CSTR + q] = pk2(v0.w, v1.w);
        }
    }
    __syncthreads();

    float* Rs = uni;          // [8][64] row sums (over x)
    float* Cs = uni + 512;    // [8][64] col sums (over y)

    // ---------------- Phase 2: Rs/Cs/Ti via b128 + shfl ---------------------
    {
        const int i = t >> 6, l = t & 63, ys = l >> 3, xb = l & 7;
        float col[8] = {0, 0, 0, 0, 0, 0, 0, 0};
        float row[8];
#pragma unroll
        for (int r = 0; r < 8; ++r) {
            const uint4 d = *reinterpret_cast<const uint4*>(
                &gxp[i * CSTR + (ys * 8 + r) * 32 + xb * 4]);
            float f0 = blo(d.x), f1 = bhi(d.x), f2 = blo(d.y), f3 = bhi(d.y);
            float f4 = blo(d.z), f5 = bhi(d.z), f6 = blo(d.w), f7 = bhi(d.w);
            row[r] = ((f0 + f1) + (f2 + f3)) + ((f4 + f5) + (f6 + f7));
            col[0] += f0; col[1] += f1; col[2] += f2; col[3] += f3;
            col[4] += f4; col[5] += f5; col[6] += f6; col[7] += f7;
        }
#pragma unroll
        for (int r = 0; r < 8; ++r) {
            float v = row[r];
            v += __shfl_xor(v, 1); v += __shfl_xor(v, 2); v += __shfl_xor(v, 4);
            if (xb == 0) Rs[i * 64 + ys * 8 + r] = v;
        }
        float tot = 0.f;
#pragma unroll
        for (int j = 0; j < 8; ++j) {
            float c = col[j];
            c += __shfl_xor(c, 8); c += __shfl_xor(c, 16); c += __shfl_xor(c, 32);
            if (ys == 0) Cs[i * 64 + xb * 8 + j] = c;
            tot += c;
        }
        tot += __shfl_xor(tot, 1); tot += __shfl_xor(tot, 2); tot += __shfl_xor(tot, 4);
        if (l == 0) Ti[i] = tot;
    }
    __syncthreads();

    // ---------------- Phase 3: gate matmul (8x8) + sigmoid ------------------
    {
        const int o = t >> 6, p = t & 63;
        float vy = b1[o], vx = b1[o];
#pragma unroll
        for (int i = 0; i < 8; ++i) {
            float wv = w1[o * 8 + i] * (1.0f / 64.0f);
            vy += wv * Rs[i * 64 + p];
            vx += wv * Cs[i * 64 + p];
        }
        sg[o * 128 + p] = sigm(vy);
        sg[o * 128 + 64 + p] = sigm(vx);
    }
    __syncthreads();

    // ---------------- Phase 4: instance-norm stats (wave i = channel i) -----
    {
        const int i = t >> 6, l = t & 63, ys = l >> 3, xb = l & 7;
        const float4 sa = *reinterpret_cast<const float4*>(&sg[i * 128 + 64 + xb * 8]);
        const float4 sb = *reinterpret_cast<const float4*>(&sg[i * 128 + 64 + xb * 8 + 4]);
        float s = 0.f, s2 = 0.f;
#pragma unroll
        for (int r = 0; r < 8; ++r) {
            const float shv = sg[i * 128 + ys * 8 + r];
            const uint4 d = *reinterpret_cast<const uint4*>(
                &gxp[i * CSTR + (ys * 8 + r) * 32 + xb * 4]);
            float g0 = blo(d.x) * shv * sa.x; s += g0; s2 += g0 * g0;
            float g1 = bhi(d.x) * shv * sa.y; s += g1; s2 += g1 * g1;
            float g2 = blo(d.y) * shv * sa.z; s += g2; s2 += g2 * g2;
            float g3 = bhi(d.y) * shv * sa.w; s += g3; s2 += g3 * g3;
            float g4 = blo(d.z) * shv * sb.x; s += g4; s2 += g4 * g4;
            float g5 = bhi(d.z) * shv * sb.y; s += g5; s2 += g5 * g5;
            float g6 = blo(d.w) * shv * sb.z; s += g6; s2 += g6 * g6;
            float g7 = bhi(d.w) * shv * sb.w; s += g7; s2 += g7 * g7;
        }
#pragma unroll
        for (int off = 32; off; off >>= 1) {
            s += __shfl_xor(s, off);
            s2 += __shfl_xor(s2, off);
        }
        if (l == 0) {
            float mu = s * (1.0f / 4096.0f);
            float var = s2 * (1.0f / 4096.0f) - mu * mu;
            float a = rsqrtf(var + 1e-5f) * gn_w[i];
            Ai[i] = a;
            Ci[i] = gn_b[i] - mu * a;
        }
    }
    // ---- Phase 5a: conv channel means from rectangle sums (wave 0) ---------
    if (t < 64) {
        const int o = t >> 3, i = t & 7;
        const float T = Ti[i];
        float part = 0.f;
#pragma unroll
        for (int ky = 0; ky < 3; ++ky) {
            int dy = ky - 1;
#pragma unroll
            for (int kx = 0; kx < 3; ++kx) {
                int dx = kx - 1;
                float S = T;
                int er = (dy < 0) ? 63 : 0;
                int ec = (dx < 0) ? 63 : 0;
                if (dy != 0) S -= Rs[i * 64 + er];
                if (dx != 0) S -= Cs[i * 64 + ec];
                if (dy != 0 && dx != 0) {
                    uint u = gxp[i * CSTR + er * 32 + (ec >> 1)];
                    S += (ec & 1) ? bhi(u) : blo(u);
                }
                part += w3[((o * 8 + i) * 3 + ky) * 3 + kx] * S;
            }
        }
        part += __shfl_xor(part, 1); part += __shfl_xor(part, 2); part += __shfl_xor(part, 4);
        if (i == 0) m2s[o] = part * (1.0f / 4096.0f) + b3[o];
    }
    // ---- Phase 5b: the two 8-way softmaxes (same wave as 5a writers) -------
    if (t < 8) {
        float mx = m2s[0];
#pragma unroll
        for (int o = 1; o < 8; ++o) mx = fmaxf(mx, m2s[o]);
        float sum = 0.f;
#pragma unroll
        for (int o = 0; o < 8; ++o) sum += __expf(m2s[o] - mx);
        x21s[t] = __expf(m2s[t] - mx) / sum;
        // x1 spatial mean == gn_b exactly (normalized field)
        float mx1 = gn_b[0];
#pragma unroll
        for (int o = 1; o < 8; ++o) mx1 = fmaxf(mx1, gn_b[o]);
        float sum1 = 0.f;
#pragma unroll
        for (int o = 0; o < 8; ++o) sum1 += __expf(gn_b[o] - mx1);
        x11s[t] = __expf(gn_b[t] - mx1) / sum1;
    }
    __syncthreads();

    // ---- Phase 5c: collapsed filter, t1, constants -------------------------
    if (t < 72) {
        const int i = t / 9, k = t % 9;
        float acc = 0.f;
#pragma unroll
        for (int o = 0; o < 8; ++o) acc += x11s[o] * w3[(o * 8 + i) * 9 + k];
        weff[i * 9 + k] = acc;
    }
    {
        const int i = t >> 6, y = t & 63;
        t1s[i * 64 + y] = x21s[i] * Ai[i] * sg[i * 128 + y];
    }
    if (t == 0) {
        float wc = 0.f;
#pragma unroll
        for (int o = 0; o < 8; ++o) wc += x11s[o] * b3[o] + x21s[o] * Ci[o];
        wconst_s = wc;
    }
    __syncthreads();

    // ---- Phase 6a: per-pixel weight field -> sigmoid (u16) into uni --------
    {
        const int y = t >> 3, xb = t & 7;       // 8 consecutive px per thread
        const ushort* gxs = reinterpret_cast<const ushort*>(gxp);
        float ws0 = wconst_s, ws1 = ws0, ws2 = ws0, ws3 = ws0;
        float ws4 = ws0, ws5 = ws0, ws6 = ws0, ws7 = ws0;
#pragma unroll
        for (int i = 0; i < 8; ++i) {
            const float t1v = t1s[i * 64 + y];
            const float4 sa = *reinterpret_cast<const float4*>(&sg[i * 128 + 64 + xb * 8]);
            const float4 sb = *reinterpret_cast<const float4*>(&sg[i * 128 + 64 + xb * 8 + 4]);
            const int xm = (xb == 0) ? 0 : (xb * 8 - 1);
            const int xp = (xb == 7) ? 63 : (xb * 8 + 8);
#pragma unroll
            for (int dy = -1; dy <= 1; ++dy) {
                const int yy = y + dy;
                if (yy < 0 || yy > 63) continue;
                const uint4 d = *reinterpret_cast<const uint4*>(
                    &gxp[i * CSTR + yy * 32 + xb * 4]);
                float f0 = blo(d.x), f1 = bhi(d.x), f2 = blo(d.y), f3 = bhi(d.y);
                float f4 = blo(d.z), f5 = bhi(d.z), f6 = blo(d.w), f7 = bhi(d.w);
                float vm = (xb == 0) ? 0.f : bfs(gxs[i * USTR + yy * 64 + xm]);
                float vp = (xb == 7) ? 0.f : bfs(gxs[i * USTR + yy * 64 + xp]);
                const float* wp = &weff[i * 9 + (dy + 1) * 3];
                const float wl = wp[0], wc = wp[1], wr = wp[2];
                ws0 += wl * vm + wc * f0 + wr * f1;
                ws1 += wl * f0 + wc * f1 + wr * f2;
                ws2 += wl * f1 + wc * f2 + wr * f3;
                ws3 += wl * f2 + wc * f3 + wr * f4;
                ws4 += wl * f3 + wc * f4 + wr * f5;
                ws5 += wl * f4 + wc * f5 + wr * f6;
                ws6 += wl * f5 + wc * f6 + wr * f7;
                ws7 += wl * f6 + wc * f7 + wr * vp;
                if (dy == 0) {
                    ws0 += t1v * sa.x * f0;  ws1 += t1v * sa.y * f1;
                    ws2 += t1v * sa.z * f2;  ws3 += t1v * sa.w * f3;
                    ws4 += t1v * sb.x * f4;  ws5 += t1v * sb.y * f5;
                    ws6 += t1v * sb.z * f6;  ws7 += t1v * sb.w * f7;
                }
            }
        }
        uint* psum = reinterpret_cast<uint*>(uni);
        const int qb = y * 32 + xb * 4;
        psum[qb + 0] = pksig(sigm(ws0), sigm(ws1));
        psum[qb + 1] = pksig(sigm(ws2), sigm(ws3));
        psum[qb + 2] = pksig(sigm(ws4), sigm(ws5));
        psum[qb + 3] = pksig(sigm(ws6), sigm(ws7));
    }
    __syncthreads();

    // ---- Phase 6b: out = gx * sig, coalesced ------------------------------
    {
        const uint* psum = reinterpret_cast<const uint*>(uni);
        float4* out4 = reinterpret_cast<float4*>(out) + (size_t)b * 4096 * 64 + g * 2;
#pragma unroll
        for (int j = 0; j < 4; ++j) {
            const int q = j * 512 + t;          // pixel pair
            const uint sp = psum[q];
            const float s0 = (float)(sp & 0xFFFFu) * (1.0f / 65535.0f);
            const float s1 = (float)(sp >> 16) * (1.0f / 65535.0f);
            const uint u0 = gxp[0 * CSTR + q], u1 = gxp[1 * CSTR + q];
            const uint u2 = gxp[2 * CSTR + q], u3 = gxp[3 * CSTR + q];
            const uint u4 = gxp[4 * CSTR + q], u5 = gxp[5 * CSTR + q];
            const uint u6 = gxp[6 * CSTR + q], u7 = gxp[7 * CSTR + q];
            float4 a0, a1, c0, c1;
            a0.x = blo(u0) * s0; a0.y = blo(u1) * s0; a0.z = blo(u2) * s0; a0.w = blo(u3) * s0;
            a1.x = blo(u4) * s0; a1.y = blo(u5) * s0; a1.z = blo(u6) * s0; a1.w = blo(u7) * s0;
            c0.x = bhi(u0) * s1; c0.y = bhi(u1) * s1; c0.z = bhi(u2) * s1; c0.w = bhi(u3) * s1;
            c1.x = bhi(u4) * s1; c1.y = bhi(u5) * s1; c1.z = bhi(u6) * s1; c1.w = bhi(u7) * s1;
            const size_t p0 = (size_t)q * 128;
            out4[p0] = a0;
            out4[p0 + 1] = a1;
            out4[p0 + 64] = c0;
            out4[p0 + 65] = c1;
        }
    }
}

extern "C" void kernel_launch(void* const* d_in, const int* in_sizes, int n_in,
                              void* d_out, int out_size, void* d_ws, size_t ws_size,
                              hipStream_t stream) {
    const float* x    = (const float*)d_in[0];
    const float* w1   = (const float*)d_in[1];
    const float* b1   = (const float*)d_in[2];
    const float* w3   = (const float*)d_in[3];
    const float* b3   = (const float*)d_in[4];
    const float* gn_w = (const float*)d_in[5];
    const float* gn_b = (const float*)d_in[6];
    float* out = (float*)d_out;

    hipLaunchKernelGGL(fused_ema_kernel, dim3(NBLK), dim3(NTHR), 0, stream,
                       x, w1, b1, w3, b3, gn_w, gn_b, out);
}